// Round 1
// baseline (1015.007 us; speedup 1.0000x reference)
//
#include <hip/hip_runtime.h>
#include <cmath>

namespace {

constexpr int CH    = 512;
constexpr int NPIX  = 4096;   // 64*64
constexpr int NB    = 8;

__device__ __forceinline__ float sigmoidf_(float v) { return 1.0f / (1.0f + expf(-v)); }

// ======================= K1: qk = x @ qk_w^T + qk_b =======================
// A: (32768, 512) row-major, W: (1024, 512) row-major, out: (32768, 1024)
// Both operands are K-contiguous ("NT" GEMM). fp32 vector FMA, 128x128x32 tile.
__global__ __launch_bounds__(256) void k_gemm(
    const float* __restrict__ A, const float* __restrict__ Wm,
    const float* __restrict__ bias, float* __restrict__ out)
{
    __shared__ float As[32][132];   // [k][m], +4 pad keeps float4 alignment
    __shared__ float Bs[32][132];   // [k][n]
    const int bm = blockIdx.x;      // 0..255
    const int bn = blockIdx.y;      // 0..7
    const int t  = threadIdx.x;
    const int tm = t >> 4;          // 0..15
    const int tn = t & 15;          // 0..15
    const float* Ab = A  + (size_t)bm * 128 * 512;
    const float* Wb = Wm + (size_t)bn * 128 * 512;

    float acc[8][8];
    #pragma unroll
    for (int i = 0; i < 8; i++)
        #pragma unroll
        for (int j = 0; j < 8; j++) acc[i][j] = 0.0f;

    float bvals[8];
    #pragma unroll
    for (int j = 0; j < 8; j++) bvals[j] = bias[bn * 128 + tn * 8 + j];

    for (int k0 = 0; k0 < 512; k0 += 32) {
        #pragma unroll
        for (int i = 0; i < 4; i++) {
            int id  = t + i * 256;        // 0..1023
            int row = id >> 3;            // 0..127
            int c4  = (id & 7) << 2;      // 0,4,..,28
            float4 va = *(const float4*)(Ab + (size_t)row * 512 + k0 + c4);
            As[c4+0][row] = va.x; As[c4+1][row] = va.y;
            As[c4+2][row] = va.z; As[c4+3][row] = va.w;
            float4 vb = *(const float4*)(Wb + (size_t)row * 512 + k0 + c4);
            Bs[c4+0][row] = vb.x; Bs[c4+1][row] = vb.y;
            Bs[c4+2][row] = vb.z; Bs[c4+3][row] = vb.w;
        }
        __syncthreads();
        #pragma unroll 8
        for (int kk = 0; kk < 32; kk++) {
            float a[8], b[8];
            *(float4*)(a)     = *(const float4*)(&As[kk][tm * 8]);
            *(float4*)(a + 4) = *(const float4*)(&As[kk][tm * 8 + 4]);
            *(float4*)(b)     = *(const float4*)(&Bs[kk][tn * 8]);
            *(float4*)(b + 4) = *(const float4*)(&Bs[kk][tn * 8 + 4]);
            #pragma unroll
            for (int i = 0; i < 8; i++)
                #pragma unroll
                for (int j = 0; j < 8; j++)
                    acc[i][j] = fmaf(a[i], b[j], acc[i][j]);
        }
        __syncthreads();
    }
    #pragma unroll
    for (int i = 0; i < 8; i++) {
        size_t row = (size_t)bm * 128 + tm * 8 + i;
        #pragma unroll
        for (int j = 0; j < 8; j += 4) {
            float4 v;
            v.x = acc[i][j]     + bvals[j];
            v.y = acc[i][j + 1] + bvals[j + 1];
            v.z = acc[i][j + 2] + bvals[j + 2];
            v.w = acc[i][j + 3] + bvals[j + 3];
            *(float4*)(out + row * 1024 + bn * 128 + tn * 8 + j) = v;
        }
    }
}

// ======================= K2: spatial gate (dwconv+bn+relu+sigmoid gate) ====
// Per (b, row h, which in {q,k}): computes s_sp[b,n] = sigmoid(sum_c y*pw)
// and pool partial sums pool[b,c] += sum_w (in * s_sp).  NHWC layout.
__global__ __launch_bounds__(512) void k_spatial(
    const float* __restrict__ qk,
    const float* __restrict__ dw_w_q, const float* __restrict__ dw_b_q,
    const float* __restrict__ bn_g_q, const float* __restrict__ bn_b_q,
    const float* __restrict__ pw_q,
    const float* __restrict__ dw_w_k, const float* __restrict__ dw_b_k,
    const float* __restrict__ bn_g_k, const float* __restrict__ bn_b_k,
    const float* __restrict__ pw_k,
    float* __restrict__ s_sp_q, float* __restrict__ s_sp_k,
    float* __restrict__ pool_q, float* __restrict__ pool_k)
{
    const int which = blockIdx.y;
    const int b = blockIdx.x >> 6;
    const int h = blockIdx.x & 63;
    const int c = threadIdx.x;
    const float* dw_w = which ? dw_w_k : dw_w_q;
    const float* dw_b = which ? dw_b_k : dw_b_q;
    const float* bn_g = which ? bn_g_k : bn_g_q;
    const float* bn_b = which ? bn_b_k : bn_b_q;
    const float* pw   = which ? pw_k   : pw_q;
    float*       s_sp = which ? s_sp_k : s_sp_q;
    float*       pool = which ? pool_k : pool_q;

    float w9[9];
    #pragma unroll
    for (int j = 0; j < 9; j++) w9[j] = dw_w[c * 9 + j];
    const float bconv = dw_b[c];
    const float bns   = bn_g[c] * (1.0f / sqrtf(1.00001f));
    const float bnb   = bn_b[c];
    const float pwc   = pw[c];

    __shared__ float wavepart[64][8];
    __shared__ float s_row[64];
    const int lane = c & 63, wid = c >> 6;
    const float* inb = qk + (size_t)b * NPIX * 1024 + (which ? 512 : 0);

    for (int w = 0; w < 64; w++) {
        float y = bconv;
        #pragma unroll
        for (int dh = -1; dh <= 1; dh++) {
            int h2 = h + dh;
            if (h2 < 0 || h2 >= 64) continue;
            const float* rowp = inb + (size_t)(h2 * 64) * 1024 + c;
            #pragma unroll
            for (int dw2 = -1; dw2 <= 1; dw2++) {
                int w2 = w + dw2;
                if (w2 < 0 || w2 >= 64) continue;
                y = fmaf(rowp[(size_t)w2 * 1024], w9[(dh + 1) * 3 + (dw2 + 1)], y);
            }
        }
        y = fmaxf(fmaf(y, bns, bnb), 0.0f);
        float contrib = y * pwc;
        #pragma unroll
        for (int o = 32; o > 0; o >>= 1) contrib += __shfl_down(contrib, o, 64);
        if (lane == 0) wavepart[w][wid] = contrib;
    }
    __syncthreads();
    if (c < 64) {
        float s = 0.0f;
        #pragma unroll
        for (int i = 0; i < 8; i++) s += wavepart[c][i];
        s = sigmoidf_(s);
        s_row[c] = s;
        s_sp[(size_t)b * NPIX + h * 64 + c] = s;
    }
    __syncthreads();
    float pacc = 0.0f;
    for (int w = 0; w < 64; w++) {
        float v = inb[(size_t)(h * 64 + w) * 1024 + c];
        pacc = fmaf(v, s_row[w], pacc);
    }
    atomicAdd(&pool[(size_t)b * CH + c], pacc);
}

// ======================= K3: channel sigmoid ===============================
// sch[b,o] = sigmoid( (sum_c pool[b,c] * W[o,c]) / 4096 )
__global__ __launch_bounds__(256) void k_chsig(
    const float* __restrict__ pool_q, const float* __restrict__ pool_k,
    const float* __restrict__ qch_w,  const float* __restrict__ kch_w,
    float* __restrict__ sch_q, float* __restrict__ sch_k)
{
    int id    = blockIdx.x;           // 0..2047
    int which = id >> 10;
    int rem   = id & 1023;
    int b     = rem >> 7;             // 0..7
    int og    = rem & 127;            // 0..127
    int wid   = threadIdx.x >> 6, lane = threadIdx.x & 63;
    int o     = og * 4 + wid;
    const float* pool = which ? pool_k : pool_q;
    const float* Wt   = which ? kch_w  : qch_w;
    float s = 0.0f;
    for (int cc = lane; cc < CH; cc += 64) s = fmaf(pool[b * CH + cc], Wt[o * CH + cc], s);
    #pragma unroll
    for (int off = 32; off > 0; off >>= 1) s += __shfl_down(s, off, 64);
    if (lane == 0)
        (which ? sch_k : sch_q)[b * CH + o] = sigmoidf_(s * (1.0f / 4096.0f));
}

// ======================= K4: gate*elu+1 + RoPE (in-place over qk) ==========
// val = qk * s_sp[n] * sch[c]; e = elu(val)+1; rope pairs (c, c^1).
// Writes back into the same half of qk (row stride 1024). k-pass also
// accumulates kmean[b,c] (raw sum over n).
__global__ __launch_bounds__(512) void k_rope(
    float* __restrict__ qk,
    const float* __restrict__ s_sp_q, const float* __restrict__ s_sp_k,
    const float* __restrict__ sch_q,  const float* __restrict__ sch_k,
    const float* __restrict__ cosT,   const float* __restrict__ sinT,
    float* __restrict__ kmean)
{
    const int which = blockIdx.y;
    const int c = threadIdx.x;
    const int pix0 = blockIdx.x * 8;        // 8 pixels per block
    const int b  = pix0 >> 12;
    const int n0 = pix0 & 4095;
    float* buf = qk + (which ? 512 : 0);
    const float* s_sp = which ? s_sp_k : s_sp_q;
    const float  sch  = (which ? sch_k : sch_q)[b * CH + c];
    const int kidx = c >> 1;
    const int odd  = c & 1;
    float kacc = 0.0f;
    #pragma unroll
    for (int p = 0; p < 8; p++) {
        int n = n0 + p;
        float ssp = s_sp[(size_t)b * NPIX + n];
        size_t idx = ((size_t)b * NPIX + n) * 1024 + c;
        float v = buf[idx] * ssp * sch;
        float e = v > 0.0f ? v + 1.0f : expf(v);
        float part = __shfl_xor(e, 1, 64);
        float cs = cosT[(size_t)n * 256 + kidx];
        float sn = sinT[(size_t)n * 256 + kidx];
        float r = odd ? fmaf(sn, part, cs * e) : fmaf(cs, e, -(sn * part));
        buf[idx] = r;
        if (which) kacc += r;
    }
    if (which) atomicAdd(&kmean[(size_t)b * CH + c], kacc);
}

// ======================= K5: kv[b,h,d,e] = sum_n k_r[n,d]*x[n,e] ===========
__global__ __launch_bounds__(256) void k_kv(
    const float* __restrict__ qk, const float* __restrict__ x,
    float* __restrict__ kv)
{
    const int bh = blockIdx.x;      // 0..127
    const int b  = bh >> 4, hh = bh & 15;
    const int n0 = blockIdx.y * 512;
    __shared__ float kt[32][33];
    __shared__ float vt[32][33];
    const int t  = threadIdx.x;
    const int e  = t & 31, d0 = (t >> 5) * 4;
    const int nn  = t >> 3;
    const int cc4 = (t & 7) * 4;
    float acc[4] = {0.f, 0.f, 0.f, 0.f};
    for (int s = 0; s < 512; s += 32) {
        size_t rowbase = ((size_t)(b * NPIX + n0 + s + nn));
        float4 kvv = *(const float4*)(qk + rowbase * 1024 + 512 + hh * 32 + cc4);
        kt[nn][cc4] = kvv.x; kt[nn][cc4+1] = kvv.y; kt[nn][cc4+2] = kvv.z; kt[nn][cc4+3] = kvv.w;
        float4 vv  = *(const float4*)(x + rowbase * 512 + hh * 32 + cc4);
        vt[nn][cc4] = vv.x; vt[nn][cc4+1] = vv.y; vt[nn][cc4+2] = vv.z; vt[nn][cc4+3] = vv.w;
        __syncthreads();
        #pragma unroll
        for (int q = 0; q < 32; q++) {
            float vq = vt[q][e];
            acc[0] = fmaf(kt[q][d0    ], vq, acc[0]);
            acc[1] = fmaf(kt[q][d0 + 1], vq, acc[1]);
            acc[2] = fmaf(kt[q][d0 + 2], vq, acc[2]);
            acc[3] = fmaf(kt[q][d0 + 3], vq, acc[3]);
        }
        __syncthreads();
    }
    #pragma unroll
    for (int i = 0; i < 4; i++)
        atomicAdd(&kv[((size_t)bh * 32 + d0 + i) * 32 + e], acc[i]);
}

// ======================= K6: out = (q_r @ kv)*z + lepe =====================
__global__ __launch_bounds__(512) void k_final(
    const float* __restrict__ qk, const float* __restrict__ x,
    const float* __restrict__ kvbuf, const float* __restrict__ kmean,
    const float* __restrict__ lepe_w, const float* __restrict__ lepe_b,
    float* __restrict__ out)
{
    const int b = blockIdx.x >> 6;
    const int h = blockIdx.x & 63;
    const int c = threadIdx.x;
    const int hh = c >> 5, e = c & 31;
    __shared__ float kv[16 * 32 * 32];
    __shared__ float qrow[512];
    #pragma unroll
    for (int i = 0; i < 32; i++)
        kv[c + i * 512] = kvbuf[(size_t)b * 16384 + c + i * 512] * (1.0f / 4096.0f);
    const float km = kmean[(size_t)b * CH + c] * (1.0f / 4096.0f);
    float w9[9];
    #pragma unroll
    for (int j = 0; j < 9; j++) w9[j] = lepe_w[c * 9 + j];
    const float lb = lepe_b[c];
    __syncthreads();

    const float* xb  = x  + (size_t)b * NPIX * 512;
    const float* qkb = qk + (size_t)b * NPIX * 1024;
    const float* kvh = kv + hh * 1024 + e;

    for (int w = 0; w < 64; w++) {
        int n = h * 64 + w;
        float qv = qkb[(size_t)n * 1024 + c];
        qrow[c] = qv;
        float den = qv * km;
        #pragma unroll
        for (int off = 16; off > 0; off >>= 1) den += __shfl_xor(den, off, 32);
        float z = 1.0f / (den + 1e-6f);
        __syncthreads();
        float num = 0.0f;
        #pragma unroll
        for (int d = 0; d < 32; d++) num = fmaf(qrow[hh * 32 + d], kvh[d * 32], num);
        float attn = num * z;
        // lepe depthwise 3x3 on x (NHWC)
        float lp = lb;
        #pragma unroll
        for (int dh = -1; dh <= 1; dh++) {
            int h2 = h + dh;
            if (h2 < 0 || h2 >= 64) continue;
            const float* rowp = xb + (size_t)(h2 * 64) * 512 + c;
            #pragma unroll
            for (int dw2 = -1; dw2 <= 1; dw2++) {
                int w2 = w + dw2;
                if (w2 < 0 || w2 >= 64) continue;
                lp = fmaf(rowp[(size_t)w2 * 512], w9[(dh + 1) * 3 + (dw2 + 1)], lp);
            }
        }
        out[((size_t)b * NPIX + n) * 512 + c] = attn + lp;
        __syncthreads();
    }
}

} // namespace

extern "C" void kernel_launch(void* const* d_in, const int* in_sizes, int n_in,
                              void* d_out, int out_size, void* d_ws, size_t ws_size,
                              hipStream_t stream)
{
    (void)in_sizes; (void)n_in; (void)out_size; (void)ws_size;
    const float* x        = (const float*)d_in[0];
    const float* qk_w     = (const float*)d_in[1];
    const float* qk_b     = (const float*)d_in[2];
    const float* qsp_dw_w = (const float*)d_in[3];
    const float* qsp_dw_b = (const float*)d_in[4];
    const float* qsp_bn_g = (const float*)d_in[5];
    const float* qsp_bn_b = (const float*)d_in[6];
    const float* qsp_pw_w = (const float*)d_in[7];
    const float* qch_w    = (const float*)d_in[8];
    const float* ksp_dw_w = (const float*)d_in[9];
    const float* ksp_dw_b = (const float*)d_in[10];
    const float* ksp_bn_g = (const float*)d_in[11];
    const float* ksp_bn_b = (const float*)d_in[12];
    const float* ksp_pw_w = (const float*)d_in[13];
    const float* kch_w    = (const float*)d_in[14];
    const float* lepe_w   = (const float*)d_in[15];
    const float* lepe_b   = (const float*)d_in[16];
    const float* rope_cos = (const float*)d_in[17];
    const float* rope_sin = (const float*)d_in[18];

    float* ws     = (float*)d_ws;
    float* qk     = ws;                       // 33554432 floats (128 MB), rope in-place
    float* s_sp_q = qk + 33554432;            // 32768
    float* s_sp_k = s_sp_q + 32768;           // 32768
    float* sch_q  = s_sp_k + 32768;           // 4096
    float* sch_k  = sch_q + 4096;             // 4096
    float* pool_q = sch_k + 4096;             // 4096  <- zeroed region starts here
    float* pool_k = pool_q + 4096;            // 4096
    float* kmean  = pool_k + 4096;            // 4096
    float* kv     = kmean + 4096;             // 131072

    // zero the atomically-accumulated buffers (ws is poisoned 0xAA each call)
    hipMemsetAsync(pool_q, 0, (size_t)(3 * 4096 + 131072) * sizeof(float), stream);

    k_gemm<<<dim3(256, 8), 256, 0, stream>>>(x, qk_w, qk_b, qk);
    k_spatial<<<dim3(512, 2), 512, 0, stream>>>(qk,
        qsp_dw_w, qsp_dw_b, qsp_bn_g, qsp_bn_b, qsp_pw_w,
        ksp_dw_w, ksp_dw_b, ksp_bn_g, ksp_bn_b, ksp_pw_w,
        s_sp_q, s_sp_k, pool_q, pool_k);
    k_chsig<<<2048, 256, 0, stream>>>(pool_q, pool_k, qch_w, kch_w, sch_q, sch_k);
    k_rope<<<dim3(4096, 2), 512, 0, stream>>>(qk, s_sp_q, s_sp_k, sch_q, sch_k,
                                              rope_cos, rope_sin, kmean);
    k_kv<<<dim3(128, 8), 256, 0, stream>>>(qk, x, kv);
    k_final<<<512, 512, 0, stream>>>(qk, x, kv, kmean, lepe_w, lepe_b, (float*)d_out);
}

// Round 2
// 773.540 us; speedup vs baseline: 1.3122x; 1.3122x over previous
//
#include <hip/hip_runtime.h>
#include <cmath>

namespace {

constexpr int CH    = 512;
constexpr int NPIX  = 4096;   // 64*64

typedef _Float16 half8 __attribute__((ext_vector_type(8)));
typedef _Float16 half4 __attribute__((ext_vector_type(4)));
typedef float    f32x4 __attribute__((ext_vector_type(4)));

__device__ __forceinline__ float sigmoidf_(float v) { return 1.0f / (1.0f + expf(-v)); }

// ======================= K0: fp32 -> (hi, lo*1024) f16 split ==============
// a = hi + lo/1024 with both halves in f16 normal range.
__global__ __launch_bounds__(256) void k_split(
    const float4* __restrict__ in, half4* __restrict__ hi,
    half4* __restrict__ lo, int n4)
{
    int i = blockIdx.x * 256 + threadIdx.x;
    if (i >= n4) return;
    float4 v = in[i];
    half4 h, l;
    h[0] = (_Float16)v.x; l[0] = (_Float16)((v.x - (float)h[0]) * 1024.0f);
    h[1] = (_Float16)v.y; l[1] = (_Float16)((v.y - (float)h[1]) * 1024.0f);
    h[2] = (_Float16)v.z; l[2] = (_Float16)((v.z - (float)h[2]) * 1024.0f);
    h[3] = (_Float16)v.w; l[3] = (_Float16)((v.w - (float)h[3]) * 1024.0f);
    hi[i] = h; lo[i] = l;
}

// ======================= K1: qk = x @ qk_w^T + qk_b (split-f16 MFMA) ======
// A: (32768,512) K-major, W: (1024,512) K-major (both hi/lo f16 buffers).
// 128x128 tile, BK=32, 4 waves, 16x16x32_f16 MFMA, dual accumulators.
__global__ __launch_bounds__(256, 2) void k_gemm_mfma(
    const _Float16* __restrict__ Ahi, const _Float16* __restrict__ Alo,
    const _Float16* __restrict__ Bhi, const _Float16* __restrict__ Blo,
    const float* __restrict__ bias, float* __restrict__ out)
{
    __shared__ _Float16 lds[4 * 128 * 32];   // Ahi | Alo | Bhi | Blo tiles
    const int t    = threadIdx.x;
    const int wave = t >> 6;
    const int lane = t & 63;
    const int bm   = blockIdx.x;             // 0..255
    const int bn   = blockIdx.y;             // 0..7

    // staging: wave w stages array w (8 x 1KB global_load_lds per K-step)
    const _Float16* src;
    switch (wave) {
        case 0: src = Ahi + (size_t)bm * 128 * 512; break;
        case 1: src = Alo + (size_t)bm * 128 * 512; break;
        case 2: src = Bhi + (size_t)bn * 128 * 512; break;
        default: src = Blo + (size_t)bn * 128 * 512; break;
    }
    const _Float16* srcLane = src + (size_t)(lane >> 2) * 512 + (lane & 3) * 8;
    _Float16* ldsW = lds + wave * 4096;

    // compute quadrant: wave (wm, wn) covers rows wm*64.., cols wn*64..
    const int wm = wave >> 1, wn = wave & 1;
    const int mrow = lane & 15;              // m (and n) index within 16-tile
    const int kq   = (lane >> 4) * 8;        // k offset for A/B fragments
    const _Float16* aH = lds         + (wm * 64 + mrow) * 32 + kq;
    const _Float16* aL = lds + 4096  + (wm * 64 + mrow) * 32 + kq;
    const _Float16* bH = lds + 8192  + (wn * 64 + mrow) * 32 + kq;
    const _Float16* bL = lds + 12288 + (wn * 64 + mrow) * 32 + kq;

    f32x4 acc0[4][4], acc1[4][4];
    #pragma unroll
    for (int i = 0; i < 4; i++)
        #pragma unroll
        for (int j = 0; j < 4; j++) { acc0[i][j] = (f32x4)0.0f; acc1[i][j] = (f32x4)0.0f; }

    for (int k0 = 0; k0 < 16; k0++) {
        const _Float16* g = srcLane + k0 * 32;
        #pragma unroll
        for (int r = 0; r < 8; r++) {
            __builtin_amdgcn_global_load_lds(
                (const __attribute__((address_space(1))) void*)(g + (size_t)r * 16 * 512),
                (__attribute__((address_space(3))) void*)(ldsW + r * 512),
                16, 0, 0);
        }
        __syncthreads();

        half8 ah[4], al[4], bh[4], bl[4];
        #pragma unroll
        for (int i = 0; i < 4; i++) {
            ah[i] = *(const half8*)(aH + i * 16 * 32);
            al[i] = *(const half8*)(aL + i * 16 * 32);
            bh[i] = *(const half8*)(bH + i * 16 * 32);
            bl[i] = *(const half8*)(bL + i * 16 * 32);
        }
        #pragma unroll
        for (int i = 0; i < 4; i++)
            #pragma unroll
            for (int j = 0; j < 4; j++) {
                acc0[i][j] = __builtin_amdgcn_mfma_f32_16x16x32_f16(ah[i], bh[j], acc0[i][j], 0, 0, 0);
                acc1[i][j] = __builtin_amdgcn_mfma_f32_16x16x32_f16(ah[i], bl[j], acc1[i][j], 0, 0, 0);
                acc1[i][j] = __builtin_amdgcn_mfma_f32_16x16x32_f16(al[i], bh[j], acc1[i][j], 0, 0, 0);
            }
        __syncthreads();
    }

    // epilogue: C/D layout col=lane&15, row=(lane>>4)*4+r
    const int ccol = lane & 15;
    const int crow = (lane >> 4) * 4;
    #pragma unroll
    for (int j = 0; j < 4; j++) {
        int col = bn * 128 + wn * 64 + j * 16 + ccol;
        float bv = bias[col];
        #pragma unroll
        for (int i = 0; i < 4; i++) {
            size_t row0 = (size_t)bm * 128 + wm * 64 + i * 16 + crow;
            #pragma unroll
            for (int r = 0; r < 4; r++) {
                float v = acc0[i][j][r] + acc1[i][j][r] * (1.0f / 1024.0f) + bv;
                out[(row0 + r) * 1024 + col] = v;
            }
        }
    }
}

// ======================= K2: spatial gate (dwconv+bn+relu+sigmoid gate) ====
__global__ __launch_bounds__(512) void k_spatial(
    const float* __restrict__ qk,
    const float* __restrict__ dw_w_q, const float* __restrict__ dw_b_q,
    const float* __restrict__ bn_g_q, const float* __restrict__ bn_b_q,
    const float* __restrict__ pw_q,
    const float* __restrict__ dw_w_k, const float* __restrict__ dw_b_k,
    const float* __restrict__ bn_g_k, const float* __restrict__ bn_b_k,
    const float* __restrict__ pw_k,
    float* __restrict__ s_sp_q, float* __restrict__ s_sp_k,
    float* __restrict__ pool_q, float* __restrict__ pool_k)
{
    const int which = blockIdx.y;
    const int b = blockIdx.x >> 6;
    const int h = blockIdx.x & 63;
    const int c = threadIdx.x;
    const float* dw_w = which ? dw_w_k : dw_w_q;
    const float* dw_b = which ? dw_b_k : dw_b_q;
    const float* bn_g = which ? bn_g_k : bn_g_q;
    const float* bn_b = which ? bn_b_k : bn_b_q;
    const float* pw   = which ? pw_k   : pw_q;
    float*       s_sp = which ? s_sp_k : s_sp_q;
    float*       pool = which ? pool_k : pool_q;

    float w9[9];
    #pragma unroll
    for (int j = 0; j < 9; j++) w9[j] = dw_w[c * 9 + j];
    const float bconv = dw_b[c];
    const float bns   = bn_g[c] * (1.0f / sqrtf(1.00001f));
    const float bnb   = bn_b[c];
    const float pwc   = pw[c];

    __shared__ float wavepart[64][8];
    __shared__ float s_row[64];
    const int lane = c & 63, wid = c >> 6;
    const float* inb = qk + (size_t)b * NPIX * 1024 + (which ? 512 : 0);

    for (int w = 0; w < 64; w++) {
        float y = bconv;
        #pragma unroll
        for (int dh = -1; dh <= 1; dh++) {
            int h2 = h + dh;
            if (h2 < 0 || h2 >= 64) continue;
            const float* rowp = inb + (size_t)(h2 * 64) * 1024 + c;
            #pragma unroll
            for (int dw2 = -1; dw2 <= 1; dw2++) {
                int w2 = w + dw2;
                if (w2 < 0 || w2 >= 64) continue;
                y = fmaf(rowp[(size_t)w2 * 1024], w9[(dh + 1) * 3 + (dw2 + 1)], y);
            }
        }
        y = fmaxf(fmaf(y, bns, bnb), 0.0f);
        float contrib = y * pwc;
        #pragma unroll
        for (int o = 32; o > 0; o >>= 1) contrib += __shfl_down(contrib, o, 64);
        if (lane == 0) wavepart[w][wid] = contrib;
    }
    __syncthreads();
    if (c < 64) {
        float s = 0.0f;
        #pragma unroll
        for (int i = 0; i < 8; i++) s += wavepart[c][i];
        s = sigmoidf_(s);
        s_row[c] = s;
        s_sp[(size_t)b * NPIX + h * 64 + c] = s;
    }
    __syncthreads();
    float pacc = 0.0f;
    for (int w = 0; w < 64; w++) {
        float v = inb[(size_t)(h * 64 + w) * 1024 + c];
        pacc = fmaf(v, s_row[w], pacc);
    }
    atomicAdd(&pool[(size_t)b * CH + c], pacc);
}

// ======================= K3: channel sigmoid ===============================
__global__ __launch_bounds__(256) void k_chsig(
    const float* __restrict__ pool_q, const float* __restrict__ pool_k,
    const float* __restrict__ qch_w,  const float* __restrict__ kch_w,
    float* __restrict__ sch_q, float* __restrict__ sch_k)
{
    int id    = blockIdx.x;           // 0..2047
    int which = id >> 10;
    int rem   = id & 1023;
    int b     = rem >> 7;             // 0..7
    int og    = rem & 127;            // 0..127
    int wid   = threadIdx.x >> 6, lane = threadIdx.x & 63;
    int o     = og * 4 + wid;
    const float* pool = which ? pool_k : pool_q;
    const float* Wt   = which ? kch_w  : qch_w;
    float s = 0.0f;
    for (int cc = lane; cc < CH; cc += 64) s = fmaf(pool[b * CH + cc], Wt[o * CH + cc], s);
    #pragma unroll
    for (int off = 32; off > 0; off >>= 1) s += __shfl_down(s, off, 64);
    if (lane == 0)
        (which ? sch_k : sch_q)[b * CH + o] = sigmoidf_(s * (1.0f / 4096.0f));
}

// ======================= K4: gate*elu+1 + RoPE (in-place over qk) ==========
__global__ __launch_bounds__(512) void k_rope(
    float* __restrict__ qk,
    const float* __restrict__ s_sp_q, const float* __restrict__ s_sp_k,
    const float* __restrict__ sch_q,  const float* __restrict__ sch_k,
    const float* __restrict__ cosT,   const float* __restrict__ sinT,
    float* __restrict__ kmean)
{
    const int which = blockIdx.y;
    const int c = threadIdx.x;
    const int pix0 = blockIdx.x * 8;        // 8 pixels per block
    const int b  = pix0 >> 12;
    const int n0 = pix0 & 4095;
    float* buf = qk + (which ? 512 : 0);
    const float* s_sp = which ? s_sp_k : s_sp_q;
    const float  sch  = (which ? sch_k : sch_q)[b * CH + c];
    const int kidx = c >> 1;
    const int odd  = c & 1;
    float kacc = 0.0f;
    #pragma unroll
    for (int p = 0; p < 8; p++) {
        int n = n0 + p;
        float ssp = s_sp[(size_t)b * NPIX + n];
        size_t idx = ((size_t)b * NPIX + n) * 1024 + c;
        float v = buf[idx] * ssp * sch;
        float e = v > 0.0f ? v + 1.0f : expf(v);
        float part = __shfl_xor(e, 1, 64);
        float cs = cosT[(size_t)n * 256 + kidx];
        float sn = sinT[(size_t)n * 256 + kidx];
        float r = odd ? fmaf(sn, part, cs * e) : fmaf(cs, e, -(sn * part));
        buf[idx] = r;
        if (which) kacc += r;
    }
    if (which) atomicAdd(&kmean[(size_t)b * CH + c], kacc);
}

// ======================= K5: kv[b,h,d,e] = sum_n k_r[n,d]*x[n,e] ===========
__global__ __launch_bounds__(256) void k_kv(
    const float* __restrict__ qk, const float* __restrict__ x,
    float* __restrict__ kv)
{
    const int bh = blockIdx.x;      // 0..127
    const int b  = bh >> 4, hh = bh & 15;
    const int n0 = blockIdx.y * 512;
    __shared__ float kt[32][33];
    __shared__ float vt[32][33];
    const int t  = threadIdx.x;
    const int e  = t & 31, d0 = (t >> 5) * 4;
    const int nn  = t >> 3;
    const int cc4 = (t & 7) * 4;
    float acc[4] = {0.f, 0.f, 0.f, 0.f};
    for (int s = 0; s < 512; s += 32) {
        size_t rowbase = ((size_t)(b * NPIX + n0 + s + nn));
        float4 kvv = *(const float4*)(qk + rowbase * 1024 + 512 + hh * 32 + cc4);
        kt[nn][cc4] = kvv.x; kt[nn][cc4+1] = kvv.y; kt[nn][cc4+2] = kvv.z; kt[nn][cc4+3] = kvv.w;
        float4 vv  = *(const float4*)(x + rowbase * 512 + hh * 32 + cc4);
        vt[nn][cc4] = vv.x; vt[nn][cc4+1] = vv.y; vt[nn][cc4+2] = vv.z; vt[nn][cc4+3] = vv.w;
        __syncthreads();
        #pragma unroll
        for (int q = 0; q < 32; q++) {
            float vq = vt[q][e];
            acc[0] = fmaf(kt[q][d0    ], vq, acc[0]);
            acc[1] = fmaf(kt[q][d0 + 1], vq, acc[1]);
            acc[2] = fmaf(kt[q][d0 + 2], vq, acc[2]);
            acc[3] = fmaf(kt[q][d0 + 3], vq, acc[3]);
        }
        __syncthreads();
    }
    #pragma unroll
    for (int i = 0; i < 4; i++)
        atomicAdd(&kv[((size_t)bh * 32 + d0 + i) * 32 + e], acc[i]);
}

// ======================= K6: out = (q_r @ kv)*z + lepe =====================
__global__ __launch_bounds__(512) void k_final(
    const float* __restrict__ qk, const float* __restrict__ x,
    const float* __restrict__ kvbuf, const float* __restrict__ kmean,
    const float* __restrict__ lepe_w, const float* __restrict__ lepe_b,
    float* __restrict__ out)
{
    const int b = blockIdx.x >> 6;
    const int h = blockIdx.x & 63;
    const int c = threadIdx.x;
    const int hh = c >> 5, e = c & 31;
    __shared__ float kv[16 * 32 * 32];
    __shared__ float qrow[512];
    #pragma unroll
    for (int i = 0; i < 32; i++)
        kv[c + i * 512] = kvbuf[(size_t)b * 16384 + c + i * 512] * (1.0f / 4096.0f);
    const float km = kmean[(size_t)b * CH + c] * (1.0f / 4096.0f);
    float w9[9];
    #pragma unroll
    for (int j = 0; j < 9; j++) w9[j] = lepe_w[c * 9 + j];
    const float lb = lepe_b[c];
    __syncthreads();

    const float* xb  = x  + (size_t)b * NPIX * 512;
    const float* qkb = qk + (size_t)b * NPIX * 1024;
    const float* kvh = kv + hh * 1024 + e;

    for (int w = 0; w < 64; w++) {
        int n = h * 64 + w;
        float qv = qkb[(size_t)n * 1024 + c];
        qrow[c] = qv;
        float den = qv * km;
        #pragma unroll
        for (int off = 16; off > 0; off >>= 1) den += __shfl_xor(den, off, 32);
        float z = 1.0f / (den + 1e-6f);
        __syncthreads();
        float num = 0.0f;
        #pragma unroll
        for (int d = 0; d < 32; d++) num = fmaf(qrow[hh * 32 + d], kvh[d * 32], num);
        float attn = num * z;
        float lp = lb;
        #pragma unroll
        for (int dh = -1; dh <= 1; dh++) {
            int h2 = h + dh;
            if (h2 < 0 || h2 >= 64) continue;
            const float* rowp = xb + (size_t)(h2 * 64) * 512 + c;
            #pragma unroll
            for (int dw2 = -1; dw2 <= 1; dw2++) {
                int w2 = w + dw2;
                if (w2 < 0 || w2 >= 64) continue;
                lp = fmaf(rowp[(size_t)w2 * 512], w9[(dh + 1) * 3 + (dw2 + 1)], lp);
            }
        }
        out[((size_t)b * NPIX + n) * 512 + c] = attn + lp;
        __syncthreads();
    }
}

} // namespace

extern "C" void kernel_launch(void* const* d_in, const int* in_sizes, int n_in,
                              void* d_out, int out_size, void* d_ws, size_t ws_size,
                              hipStream_t stream)
{
    (void)in_sizes; (void)n_in; (void)out_size; (void)ws_size;
    const float* x        = (const float*)d_in[0];
    const float* qk_w     = (const float*)d_in[1];
    const float* qk_b     = (const float*)d_in[2];
    const float* qsp_dw_w = (const float*)d_in[3];
    const float* qsp_dw_b = (const float*)d_in[4];
    const float* qsp_bn_g = (const float*)d_in[5];
    const float* qsp_bn_b = (const float*)d_in[6];
    const float* qsp_pw_w = (const float*)d_in[7];
    const float* qch_w    = (const float*)d_in[8];
    const float* ksp_dw_w = (const float*)d_in[9];
    const float* ksp_dw_b = (const float*)d_in[10];
    const float* ksp_bn_g = (const float*)d_in[11];
    const float* ksp_bn_b = (const float*)d_in[12];
    const float* ksp_pw_w = (const float*)d_in[13];
    const float* kch_w    = (const float*)d_in[14];
    const float* lepe_w   = (const float*)d_in[15];
    const float* lepe_b   = (const float*)d_in[16];
    const float* rope_cos = (const float*)d_in[17];
    const float* rope_sin = (const float*)d_in[18];

    float* ws     = (float*)d_ws;
    float* qk     = ws;                       // 33554432 floats (128 MB)
    float* s_sp_q = qk + 33554432;            // 32768
    float* s_sp_k = s_sp_q + 32768;           // 32768
    float* sch_q  = s_sp_k + 32768;           // 4096
    float* sch_k  = sch_q + 4096;             // 4096
    float* pool_q = sch_k + 4096;             // 4096  <- zeroed region starts here
    float* pool_k = pool_q + 4096;            // 4096
    float* kmean  = pool_k + 4096;            // 4096
    float* kv     = kmean + 4096;             // 131072
    // f16 split buffers (after the float region)
    _Float16* x_hi = (_Float16*)(kv + 131072);     // 16777216 halfs (32 MB)
    _Float16* x_lo = x_hi + 16777216;              // 32 MB
    _Float16* w_hi = x_lo + 16777216;              // 524288 halfs (1 MB)
    _Float16* w_lo = w_hi + 524288;                // 1 MB

    hipMemsetAsync(pool_q, 0, (size_t)(3 * 4096 + 131072) * sizeof(float), stream);

    k_split<<<16384, 256, 0, stream>>>((const float4*)x, (half4*)x_hi, (half4*)x_lo, 4194304);
    k_split<<<512, 256, 0, stream>>>((const float4*)qk_w, (half4*)w_hi, (half4*)w_lo, 131072);
    k_gemm_mfma<<<dim3(256, 8), 256, 0, stream>>>(x_hi, x_lo, w_hi, w_lo, qk_b, qk);

    k_spatial<<<dim3(512, 2), 512, 0, stream>>>(qk,
        qsp_dw_w, qsp_dw_b, qsp_bn_g, qsp_bn_b, qsp_pw_w,
        ksp_dw_w, ksp_dw_b, ksp_bn_g, ksp_bn_b, ksp_pw_w,
        s_sp_q, s_sp_k, pool_q, pool_k);
    k_chsig<<<2048, 256, 0, stream>>>(pool_q, pool_k, qch_w, kch_w, sch_q, sch_k);
    k_rope<<<dim3(4096, 2), 512, 0, stream>>>(qk, s_sp_q, s_sp_k, sch_q, sch_k,
                                              rope_cos, rope_sin, kmean);
    k_kv<<<dim3(128, 8), 256, 0, stream>>>(qk, x, kv);
    k_final<<<512, 512, 0, stream>>>(qk, x, kv, kmean, lepe_w, lepe_b, (float*)d_out);
}

// Round 3
// 553.582 us; speedup vs baseline: 1.8335x; 1.3973x over previous
//
#include <hip/hip_runtime.h>
#include <cmath>

namespace {

constexpr int CH    = 512;
constexpr int NPIX  = 4096;   // 64*64

typedef _Float16 half8 __attribute__((ext_vector_type(8)));
typedef _Float16 half4 __attribute__((ext_vector_type(4)));
typedef float    f32x4 __attribute__((ext_vector_type(4)));

__device__ __forceinline__ float sigmoidf_(float v) { return 1.0f / (1.0f + expf(-v)); }

// ======================= K0: fp32 -> (hi, lo*1024) f16 split ==============
__global__ __launch_bounds__(256) void k_split(
    const float4* __restrict__ in, half4* __restrict__ hi,
    half4* __restrict__ lo, int n4)
{
    int i = blockIdx.x * 256 + threadIdx.x;
    if (i >= n4) return;
    float4 v = in[i];
    half4 h, l;
    h[0] = (_Float16)v.x; l[0] = (_Float16)((v.x - (float)h[0]) * 1024.0f);
    h[1] = (_Float16)v.y; l[1] = (_Float16)((v.y - (float)h[1]) * 1024.0f);
    h[2] = (_Float16)v.z; l[2] = (_Float16)((v.z - (float)h[2]) * 1024.0f);
    h[3] = (_Float16)v.w; l[3] = (_Float16)((v.w - (float)h[3]) * 1024.0f);
    hi[i] = h; lo[i] = l;
}

// ======================= K1: qk = x @ qk_w^T + qk_b (split-f16 MFMA) ======
__global__ __launch_bounds__(256, 2) void k_gemm_mfma(
    const _Float16* __restrict__ Ahi, const _Float16* __restrict__ Alo,
    const _Float16* __restrict__ Bhi, const _Float16* __restrict__ Blo,
    const float* __restrict__ bias, float* __restrict__ out)
{
    __shared__ _Float16 lds[4 * 128 * 32];   // Ahi | Alo | Bhi | Blo tiles
    const int t    = threadIdx.x;
    const int wave = t >> 6;
    const int lane = t & 63;
    const int bm   = blockIdx.x;             // 0..255
    const int bn   = blockIdx.y;             // 0..7

    const _Float16* src;
    switch (wave) {
        case 0: src = Ahi + (size_t)bm * 128 * 512; break;
        case 1: src = Alo + (size_t)bm * 128 * 512; break;
        case 2: src = Bhi + (size_t)bn * 128 * 512; break;
        default: src = Blo + (size_t)bn * 128 * 512; break;
    }
    const _Float16* srcLane = src + (size_t)(lane >> 2) * 512 + (lane & 3) * 8;
    _Float16* ldsW = lds + wave * 4096;

    const int wm = wave >> 1, wn = wave & 1;
    const int mrow = lane & 15;
    const int kq   = (lane >> 4) * 8;
    const _Float16* aH = lds         + (wm * 64 + mrow) * 32 + kq;
    const _Float16* aL = lds + 4096  + (wm * 64 + mrow) * 32 + kq;
    const _Float16* bH = lds + 8192  + (wn * 64 + mrow) * 32 + kq;
    const _Float16* bL = lds + 12288 + (wn * 64 + mrow) * 32 + kq;

    f32x4 acc0[4][4], acc1[4][4];
    #pragma unroll
    for (int i = 0; i < 4; i++)
        #pragma unroll
        for (int j = 0; j < 4; j++) { acc0[i][j] = (f32x4)0.0f; acc1[i][j] = (f32x4)0.0f; }

    for (int k0 = 0; k0 < 16; k0++) {
        const _Float16* g = srcLane + k0 * 32;
        #pragma unroll
        for (int r = 0; r < 8; r++) {
            __builtin_amdgcn_global_load_lds(
                (const __attribute__((address_space(1))) void*)(g + (size_t)r * 16 * 512),
                (__attribute__((address_space(3))) void*)(ldsW + r * 512),
                16, 0, 0);
        }
        __syncthreads();

        half8 ah[4], al[4], bh[4], bl[4];
        #pragma unroll
        for (int i = 0; i < 4; i++) {
            ah[i] = *(const half8*)(aH + i * 16 * 32);
            al[i] = *(const half8*)(aL + i * 16 * 32);
            bh[i] = *(const half8*)(bH + i * 16 * 32);
            bl[i] = *(const half8*)(bL + i * 16 * 32);
        }
        #pragma unroll
        for (int i = 0; i < 4; i++)
            #pragma unroll
            for (int j = 0; j < 4; j++) {
                acc0[i][j] = __builtin_amdgcn_mfma_f32_16x16x32_f16(ah[i], bh[j], acc0[i][j], 0, 0, 0);
                acc1[i][j] = __builtin_amdgcn_mfma_f32_16x16x32_f16(ah[i], bl[j], acc1[i][j], 0, 0, 0);
                acc1[i][j] = __builtin_amdgcn_mfma_f32_16x16x32_f16(al[i], bh[j], acc1[i][j], 0, 0, 0);
            }
        __syncthreads();
    }

    const int ccol = lane & 15;
    const int crow = (lane >> 4) * 4;
    #pragma unroll
    for (int j = 0; j < 4; j++) {
        int col = bn * 128 + wn * 64 + j * 16 + ccol;
        float bv = bias[col];
        #pragma unroll
        for (int i = 0; i < 4; i++) {
            size_t row0 = (size_t)bm * 128 + wm * 64 + i * 16 + crow;
            #pragma unroll
            for (int r = 0; r < 4; r++) {
                float v = acc0[i][j][r] + acc1[i][j][r] * (1.0f / 1024.0f) + bv;
                out[(row0 + r) * 1024 + col] = v;
            }
        }
    }
}

// ======================= K2: spatial gate — sliding window, w-quartered ====
// Block = (b, h, wq, which); 512 threads = channels. 3 loads/pixel via
// sliding 3x3 window; center values kept in regs for the pool pass (no
// second global read).
__global__ __launch_bounds__(512) void k_spatial(
    const float* __restrict__ qk,
    const float* __restrict__ dw_w_q, const float* __restrict__ dw_b_q,
    const float* __restrict__ bn_g_q, const float* __restrict__ bn_b_q,
    const float* __restrict__ pw_q,
    const float* __restrict__ dw_w_k, const float* __restrict__ dw_b_k,
    const float* __restrict__ bn_g_k, const float* __restrict__ bn_b_k,
    const float* __restrict__ pw_k,
    float* __restrict__ s_sp_q, float* __restrict__ s_sp_k,
    float* __restrict__ pool_q, float* __restrict__ pool_k)
{
    const int which = blockIdx.y;
    const int bx = blockIdx.x;            // 0..2047
    const int b  = bx >> 8;
    const int h  = (bx >> 2) & 63;
    const int w0 = (bx & 3) * 16;
    const int c  = threadIdx.x;
    const float* dw_w = which ? dw_w_k : dw_w_q;
    const float* dw_b = which ? dw_b_k : dw_b_q;
    const float* bn_g = which ? bn_g_k : bn_g_q;
    const float* bn_b = which ? bn_b_k : bn_b_q;
    const float* pw   = which ? pw_k   : pw_q;
    float*       s_sp = which ? s_sp_k : s_sp_q;
    float*       pool = which ? pool_k : pool_q;

    float w9[9];
    #pragma unroll
    for (int j = 0; j < 9; j++) w9[j] = dw_w[c * 9 + j];
    const float bconv = dw_b[c];
    const float bns   = bn_g[c] * (1.0f / sqrtf(1.00001f));
    const float bnb   = bn_b[c];
    const float pwc   = pw[c];

    __shared__ float wavepart[16][8];
    __shared__ float s_row[16];
    const int lane = c & 63, wid = c >> 6;
    const float* inb  = qk + (size_t)b * NPIX * 1024 + (which ? 512 : 0);
    const float* row0 = inb + (size_t)(h * 64) * 1024 + c;
    const float* rowm = row0 - (ptrdiff_t)64 * 1024;   // h-1 (deref-guarded)
    const float* rowp = row0 + (ptrdiff_t)64 * 1024;   // h+1
    const bool hm_ok = (h > 0), hp_ok = (h < 63);

    float x0m, x00, x0p, x1m, x10, x1p, x2m, x20, x2p;
    float cent[16];

    auto LD3 = [&](int wg, float& vm, float& v0, float& vp) {
        bool wok = (wg >= 0) && (wg < 64);
        ptrdiff_t o = (ptrdiff_t)wg * 1024;
        vm = (wok && hm_ok) ? rowm[o] : 0.0f;
        v0 =  wok           ? row0[o] : 0.0f;
        vp = (wok && hp_ok) ? rowp[o] : 0.0f;
    };

    LD3(w0 - 1, x0m, x1m, x2m);
    LD3(w0,     x00, x10, x20);

    #pragma unroll
    for (int i = 0; i < 16; i++) {
        LD3(w0 + i + 1, x0p, x1p, x2p);
        float y = bconv;
        y = fmaf(x0m, w9[0], y); y = fmaf(x00, w9[1], y); y = fmaf(x0p, w9[2], y);
        y = fmaf(x1m, w9[3], y); y = fmaf(x10, w9[4], y); y = fmaf(x1p, w9[5], y);
        y = fmaf(x2m, w9[6], y); y = fmaf(x20, w9[7], y); y = fmaf(x2p, w9[8], y);
        y = fmaxf(fmaf(y, bns, bnb), 0.0f);
        cent[i] = x10;
        float contrib = y * pwc;
        #pragma unroll
        for (int o = 32; o > 0; o >>= 1) contrib += __shfl_down(contrib, o, 64);
        if (lane == 0) wavepart[i][wid] = contrib;
        x0m = x00; x00 = x0p;
        x1m = x10; x10 = x1p;
        x2m = x20; x20 = x2p;
    }
    __syncthreads();
    if (c < 16) {
        float s = 0.0f;
        #pragma unroll
        for (int j = 0; j < 8; j++) s += wavepart[c][j];
        s = sigmoidf_(s);
        s_row[c] = s;
        s_sp[(size_t)b * NPIX + h * 64 + w0 + c] = s;
    }
    __syncthreads();
    float pacc = 0.0f;
    #pragma unroll
    for (int i = 0; i < 16; i++) pacc = fmaf(cent[i], s_row[i], pacc);
    atomicAdd(&pool[(size_t)b * CH + c], pacc);
}

// ======================= K3: channel sigmoid ===============================
__global__ __launch_bounds__(256) void k_chsig(
    const float* __restrict__ pool_q, const float* __restrict__ pool_k,
    const float* __restrict__ qch_w,  const float* __restrict__ kch_w,
    float* __restrict__ sch_q, float* __restrict__ sch_k)
{
    int id    = blockIdx.x;           // 0..2047
    int which = id >> 10;
    int rem   = id & 1023;
    int b     = rem >> 7;             // 0..7
    int og    = rem & 127;            // 0..127
    int wid   = threadIdx.x >> 6, lane = threadIdx.x & 63;
    int o     = og * 4 + wid;
    const float* pool = which ? pool_k : pool_q;
    const float* Wt   = which ? kch_w  : qch_w;
    float s = 0.0f;
    for (int cc = lane; cc < CH; cc += 64) s = fmaf(pool[b * CH + cc], Wt[o * CH + cc], s);
    #pragma unroll
    for (int off = 32; off > 0; off >>= 1) s += __shfl_down(s, off, 64);
    if (lane == 0)
        (which ? sch_k : sch_q)[b * CH + o] = sigmoidf_(s * (1.0f / 4096.0f));
}

// ======================= K4: gate*elu+1 + RoPE (in-place over qk) ==========
__global__ __launch_bounds__(512) void k_rope(
    float* __restrict__ qk,
    const float* __restrict__ s_sp_q, const float* __restrict__ s_sp_k,
    const float* __restrict__ sch_q,  const float* __restrict__ sch_k,
    const float* __restrict__ cosT,   const float* __restrict__ sinT,
    float* __restrict__ kmean)
{
    const int which = blockIdx.y;
    const int c = threadIdx.x;
    const int pix0 = blockIdx.x * 8;        // 8 pixels per block
    const int b  = pix0 >> 12;
    const int n0 = pix0 & 4095;
    float* buf = qk + (which ? 512 : 0);
    const float* s_sp = which ? s_sp_k : s_sp_q;
    const float  sch  = (which ? sch_k : sch_q)[b * CH + c];
    const int kidx = c >> 1;
    const int odd  = c & 1;
    float kacc = 0.0f;
    #pragma unroll
    for (int p = 0; p < 8; p++) {
        int n = n0 + p;
        float ssp = s_sp[(size_t)b * NPIX + n];
        size_t idx = ((size_t)b * NPIX + n) * 1024 + c;
        float v = buf[idx] * ssp * sch;
        float e = v > 0.0f ? v + 1.0f : expf(v);
        float part = __shfl_xor(e, 1, 64);
        float cs = cosT[(size_t)n * 256 + kidx];
        float sn = sinT[(size_t)n * 256 + kidx];
        float r = odd ? fmaf(sn, part, cs * e) : fmaf(cs, e, -(sn * part));
        buf[idx] = r;
        if (which) kacc += r;
    }
    if (which) atomicAdd(&kmean[(size_t)b * CH + c], kacc);
}

// ======================= K5: kv[b,h,d,e] = sum_n k_r[n,d]*x[n,e] ===========
__global__ __launch_bounds__(256) void k_kv(
    const float* __restrict__ qk, const float* __restrict__ x,
    float* __restrict__ kv)
{
    const int bh = blockIdx.x;      // 0..127
    const int b  = bh >> 4, hh = bh & 15;
    const int n0 = blockIdx.y * 512;
    __shared__ float kt[32][33];
    __shared__ float vt[32][33];
    const int t  = threadIdx.x;
    const int e  = t & 31, d0 = (t >> 5) * 4;
    const int nn  = t >> 3;
    const int cc4 = (t & 7) * 4;
    float acc[4] = {0.f, 0.f, 0.f, 0.f};
    for (int s = 0; s < 512; s += 32) {
        size_t rowbase = ((size_t)(b * NPIX + n0 + s + nn));
        float4 kvv = *(const float4*)(qk + rowbase * 1024 + 512 + hh * 32 + cc4);
        kt[nn][cc4] = kvv.x; kt[nn][cc4+1] = kvv.y; kt[nn][cc4+2] = kvv.z; kt[nn][cc4+3] = kvv.w;
        float4 vv  = *(const float4*)(x + rowbase * 512 + hh * 32 + cc4);
        vt[nn][cc4] = vv.x; vt[nn][cc4+1] = vv.y; vt[nn][cc4+2] = vv.z; vt[nn][cc4+3] = vv.w;
        __syncthreads();
        #pragma unroll
        for (int q = 0; q < 32; q++) {
            float vq = vt[q][e];
            acc[0] = fmaf(kt[q][d0    ], vq, acc[0]);
            acc[1] = fmaf(kt[q][d0 + 1], vq, acc[1]);
            acc[2] = fmaf(kt[q][d0 + 2], vq, acc[2]);
            acc[3] = fmaf(kt[q][d0 + 3], vq, acc[3]);
        }
        __syncthreads();
    }
    #pragma unroll
    for (int i = 0; i < 4; i++)
        atomicAdd(&kv[((size_t)bh * 32 + d0 + i) * 32 + e], acc[i]);
}

// ======================= K6: out = (q_r @ kv)*z + lepe — shfl, no LDS ======
// Block = (b, h, w-half); 512 threads = channels. kv column in registers,
// q broadcast via width-32 shfl (one head per 32-lane group), sliding-window
// lepe conv. Zero __syncthreads.
__global__ __launch_bounds__(512) void k_final(
    const float* __restrict__ qk, const float* __restrict__ x,
    const float* __restrict__ kvbuf, const float* __restrict__ kmean,
    const float* __restrict__ lepe_w, const float* __restrict__ lepe_b,
    float* __restrict__ out)
{
    const int bx = blockIdx.x;            // 0..1023
    const int b  = bx >> 7;
    const int h  = (bx >> 1) & 63;
    const int w0 = (bx & 1) * 32;
    const int c  = threadIdx.x;
    const int e  = c & 31;
    const int head = c >> 5;

    float kvreg[32];
    #pragma unroll
    for (int d = 0; d < 32; d++)
        kvreg[d] = kvbuf[((size_t)b * 16 + head) * 1024 + d * 32 + e] * (1.0f / 4096.0f);
    const float km = kmean[(size_t)b * CH + c] * (1.0f / 4096.0f);
    float w9[9];
    #pragma unroll
    for (int j = 0; j < 9; j++) w9[j] = lepe_w[c * 9 + j];
    const float lb = lepe_b[c];

    const float* xr0 = x + ((size_t)b * NPIX + h * 64) * 512 + c;
    const float* xrm = xr0 - (ptrdiff_t)64 * 512;
    const float* xrp = xr0 + (ptrdiff_t)64 * 512;
    const bool hm_ok = (h > 0), hp_ok = (h < 63);
    const float* qkb = qk + ((size_t)b * NPIX + h * 64) * 1024 + c;
    float* outb = out + ((size_t)b * NPIX + h * 64) * 512 + c;

    float x0m, x00, x0p, x1m, x10, x1p, x2m, x20, x2p;
    auto LD3 = [&](int wg, float& vm, float& v0, float& vp) {
        bool wok = (wg >= 0) && (wg < 64);
        ptrdiff_t o = (ptrdiff_t)wg * 512;
        vm = (wok && hm_ok) ? xrm[o] : 0.0f;
        v0 =  wok           ? xr0[o] : 0.0f;
        vp = (wok && hp_ok) ? xrp[o] : 0.0f;
    };
    LD3(w0 - 1, x0m, x1m, x2m);
    LD3(w0,     x00, x10, x20);

    for (int i = 0; i < 32; i++) {
        const int wg = w0 + i;
        float x0p_, x1p_, x2p_;
        LD3(wg + 1, x0p_, x1p_, x2p_);
        x0p = x0p_; x1p = x1p_; x2p = x2p_;

        float qv = qkb[(size_t)wg * 1024];
        float den = qv * km;
        #pragma unroll
        for (int off = 16; off > 0; off >>= 1) den += __shfl_xor(den, off, 32);
        float z = 1.0f / (den + 1e-6f);
        float num = 0.0f;
        #pragma unroll
        for (int d = 0; d < 32; d++) num = fmaf(__shfl(qv, d, 32), kvreg[d], num);

        float lp = lb;
        lp = fmaf(x0m, w9[0], lp); lp = fmaf(x00, w9[1], lp); lp = fmaf(x0p, w9[2], lp);
        lp = fmaf(x1m, w9[3], lp); lp = fmaf(x10, w9[4], lp); lp = fmaf(x1p, w9[5], lp);
        lp = fmaf(x2m, w9[6], lp); lp = fmaf(x20, w9[7], lp); lp = fmaf(x2p, w9[8], lp);

        outb[(size_t)wg * 512] = fmaf(num, z, lp);

        x0m = x00; x00 = x0p;
        x1m = x10; x10 = x1p;
        x2m = x20; x20 = x2p;
    }
}

} // namespace

extern "C" void kernel_launch(void* const* d_in, const int* in_sizes, int n_in,
                              void* d_out, int out_size, void* d_ws, size_t ws_size,
                              hipStream_t stream)
{
    (void)in_sizes; (void)n_in; (void)out_size; (void)ws_size;
    const float* x        = (const float*)d_in[0];
    const float* qk_w     = (const float*)d_in[1];
    const float* qk_b     = (const float*)d_in[2];
    const float* qsp_dw_w = (const float*)d_in[3];
    const float* qsp_dw_b = (const float*)d_in[4];
    const float* qsp_bn_g = (const float*)d_in[5];
    const float* qsp_bn_b = (const float*)d_in[6];
    const float* qsp_pw_w = (const float*)d_in[7];
    const float* qch_w    = (const float*)d_in[8];
    const float* ksp_dw_w = (const float*)d_in[9];
    const float* ksp_dw_b = (const float*)d_in[10];
    const float* ksp_bn_g = (const float*)d_in[11];
    const float* ksp_bn_b = (const float*)d_in[12];
    const float* ksp_pw_w = (const float*)d_in[13];
    const float* kch_w    = (const float*)d_in[14];
    const float* lepe_w   = (const float*)d_in[15];
    const float* lepe_b   = (const float*)d_in[16];
    const float* rope_cos = (const float*)d_in[17];
    const float* rope_sin = (const float*)d_in[18];

    float* ws     = (float*)d_ws;
    float* qk     = ws;                       // 33554432 floats (128 MB)
    float* s_sp_q = qk + 33554432;            // 32768
    float* s_sp_k = s_sp_q + 32768;           // 32768
    float* sch_q  = s_sp_k + 32768;           // 4096
    float* sch_k  = sch_q + 4096;             // 4096
    float* pool_q = sch_k + 4096;             // 4096  <- zeroed region starts here
    float* pool_k = pool_q + 4096;            // 4096
    float* kmean  = pool_k + 4096;            // 4096
    float* kv     = kmean + 4096;             // 131072
    _Float16* x_hi = (_Float16*)(kv + 131072);     // 32 MB
    _Float16* x_lo = x_hi + 16777216;              // 32 MB
    _Float16* w_hi = x_lo + 16777216;              // 1 MB
    _Float16* w_lo = w_hi + 524288;                // 1 MB

    hipMemsetAsync(pool_q, 0, (size_t)(3 * 4096 + 131072) * sizeof(float), stream);

    k_split<<<16384, 256, 0, stream>>>((const float4*)x, (half4*)x_hi, (half4*)x_lo, 4194304);
    k_split<<<512, 256, 0, stream>>>((const float4*)qk_w, (half4*)w_hi, (half4*)w_lo, 131072);
    k_gemm_mfma<<<dim3(256, 8), 256, 0, stream>>>(x_hi, x_lo, w_hi, w_lo, qk_b, qk);

    k_spatial<<<dim3(2048, 2), 512, 0, stream>>>(qk,
        qsp_dw_w, qsp_dw_b, qsp_bn_g, qsp_bn_b, qsp_pw_w,
        ksp_dw_w, ksp_dw_b, ksp_bn_g, ksp_bn_b, ksp_pw_w,
        s_sp_q, s_sp_k, pool_q, pool_k);
    k_chsig<<<2048, 256, 0, stream>>>(pool_q, pool_k, qch_w, kch_w, sch_q, sch_k);
    k_rope<<<dim3(4096, 2), 512, 0, stream>>>(qk, s_sp_q, s_sp_k, sch_q, sch_k,
                                              rope_cos, rope_sin, kmean);
    k_kv<<<dim3(128, 8), 256, 0, stream>>>(qk, x, kv);
    k_final<<<1024, 512, 0, stream>>>(qk, x, kv, kmean, lepe_w, lepe_b, (float*)d_out);
}